// Round 3
// baseline (239.704 us; speedup 1.0000x reference)
//
#include <hip/hip_runtime.h>
#include <hip/hip_bf16.h>

// B=2048, N=64, C=256, F=256
// out[b,n,f] = d[f,n]*h0[b,n,f] + sum_m off[f,n,m]*h1[b,m,f] + bias[f]
// v3: k_pre (softmax-prep + Wt + x->bf16 xb, one kernel) then fused k_main
// with 256-thr blocks (4 batches x 32 f), direct bf16 A-frag loads with
// prefetch, einsum on LDS-resident h1, single out write.

typedef __attribute__((ext_vector_type(8))) short  fragA;   // 8 bf16 = 4 VGPR
typedef __attribute__((ext_vector_type(4))) float  f32x4;
typedef __attribute__((ext_vector_type(8))) unsigned short u16x8;
typedef __attribute__((ext_vector_type(4))) unsigned short u16x4;

// workspace layout (bytes)
constexpr long OFF_OFF = 0;                          // bf16 off [256][64][64] (2 MB)
constexpr long OFF_WT  = 2l * 1024 * 1024;           // bf16 Wt flat [512][256] (256 KB)
constexpr long OFF_DS  = OFF_WT + 512l * 256 * 2;    // f32 dscale [64][256]   (64 KB)
constexpr long OFF_XB  = OFF_DS + 64l * 256 * 4;     // bf16 xb [131072][256]  (67 MB)
constexpr long WS_NEED = OFF_XB + 131072l * 256 * 2;

static __device__ inline unsigned short f2bf(float f) {
  __hip_bfloat16 h = __float2bfloat16(f);
  return __builtin_bit_cast(unsigned short, h);
}
static __device__ inline float bf2f(unsigned short u) {
  unsigned int x = ((unsigned int)u) << 16;
  return __builtin_bit_cast(float, x);
}

// ---------------------------------------------------------------- k_pre
// blocks 0..4095: softmax prep (4 (f,n)-rows per block)
// blocks 4096..6143: x -> bf16 grid-stride
// blocks 6144..6175: W -> Wt bf16 transpose
__global__ __launch_bounds__(256) void k_pre(const float* __restrict__ x,
                                             const float* __restrict__ e,
                                             const float* __restrict__ W,
                                             const unsigned char* __restrict__ mask,
                                             char* __restrict__ ws_b) {
  const int bid = blockIdx.x;
  const int tid = threadIdx.x;
  if (bid < 4096) {
    unsigned short* off = (unsigned short*)(ws_b + OFF_OFF);
    float* dscale = (float*)(ws_b + OFF_DS);
    const int lane = tid & 63;
    const int row  = bid * 4 + (tid >> 6);   // f*64 + n
    const int n = row & 63;
    // mask dtype sniff: diag guaranteed true (self-loops)
    bool is_u8 = __all(mask[lane * 65] != 0);
    bool mv;
    if (is_u8) mv = mask[n * 64 + lane] != 0;
    else       mv = ((const int*)mask)[n * 64 + lane] != 0;
    float v = mv ? e[(long)row * 64 + lane] : -1e30f;
    float mx = v;
#pragma unroll
    for (int s = 32; s; s >>= 1) mx = fmaxf(mx, __shfl_xor(mx, s));
    float ex = mv ? __expf(v - mx) : 0.f;
    float sm = ex;
#pragma unroll
    for (int s = 32; s; s >>= 1) sm += __shfl_xor(sm, s);
    float adj = ex / sm;
    const int f = row >> 6;
    if (lane == n) dscale[n * 256 + f] = adj;
    off[(long)row * 64 + lane] = f2bf(lane == n ? 0.f : adj);
  } else if (bid < 6144) {
    unsigned short* xb = (unsigned short*)(ws_b + OFF_XB);
    long i = ((long)(bid - 4096) * 256 + tid) * 8;
    const long stride = 2048l * 256 * 8;
    const long total = 131072l * 256;
    for (; i < total; i += stride) {
      float4 a = *(const float4*)(x + i);
      float4 b = *(const float4*)(x + i + 4);
      u16x8 p;
      p[0] = f2bf(a.x); p[1] = f2bf(a.y); p[2] = f2bf(a.z); p[3] = f2bf(a.w);
      p[4] = f2bf(b.x); p[5] = f2bf(b.y); p[6] = f2bf(b.z); p[7] = f2bf(b.w);
      *(u16x8*)(xb + i) = p;
    }
  } else {
    unsigned short* Wt = (unsigned short*)(ws_b + OFF_WT);
    __shared__ float t[64][65];
    const int b2 = bid - 6144;          // 32 blocks: w(2) x f0(4) x c0(4)
    const int w = b2 >> 4, f0 = ((b2 >> 2) & 3) * 64, c0 = (b2 & 3) * 64;
    const int tr = tid >> 2, tc = (tid & 3) * 16;
    const float* src = W + ((long)(w * 256 + c0 + tr)) * 256 + f0 + tc;
#pragma unroll
    for (int i = 0; i < 16; i += 4) {
      float4 v = *(const float4*)(src + i);
      t[tr][tc + i] = v.x; t[tr][tc + i + 1] = v.y;
      t[tr][tc + i + 2] = v.z; t[tr][tc + i + 3] = v.w;
    }
    __syncthreads();
    u16x8 p0, p1;
#pragma unroll
    for (int i = 0; i < 8; i++)  p0[i] = f2bf(t[tc + i][tr]);
#pragma unroll
    for (int i = 0; i < 8; i++)  p1[i] = f2bf(t[tc + 8 + i][tr]);
    unsigned short* dst = Wt + ((long)(w * 256 + f0 + tr)) * 256 + c0 + tc;
    *(u16x8*)dst = p0;
    *(u16x8*)(dst + 8) = p1;
  }
}

// ---------------------------------------------------------------- k_main
// grid 4096, block 256 (4 waves). Block = 4 batches x 32 f; wave = 1 batch.
// GEMM 256 rows x 64 cols (32 h0-f + 32 h1-f), K=256, A direct from xb.
__global__ __launch_bounds__(256, 3) void k_main(const float* __restrict__ bias,
                                                 const char* __restrict__ ws_b,
                                                 float* __restrict__ out) {
  const unsigned short* Wt   = (const unsigned short*)(ws_b + OFF_WT);
  const unsigned short* offp = (const unsigned short*)(ws_b + OFF_OFF);
  const unsigned short* xb   = (const unsigned short*)(ws_b + OFF_XB);
  const float* dscale        = (const float*)(ws_b + OFF_DS);

  __shared__ __align__(16) unsigned short Bs[64 * 264];   // 33792 B
  __shared__ __align__(16) unsigned short Hb[32 * 296];   // 18944 B [fl][b*72][m]

  const int tid = threadIdx.x;
  const int wid = tid >> 6, lane = tid & 63;
  const int lr = lane & 15, qu = lane >> 4;

  // XCD-aware remap: same-bb fb-siblings land adjacently on one XCD.
  const int wg = blockIdx.x;
  const int xcd = wg & 7, s = wg >> 3;           // s in 0..511
  const int bb = xcd * 64 + (s >> 3);            // 0..511 (4-batch groups)
  const int fb = s & 7;                          // 0..7
  const int f0 = fb * 32;
  const long R0 = (long)bb * 256;                // 256 rows per block
  const long Rw = R0 + wid * 64;                 // wave's 64 rows (1 batch)

  // ---- stage B tile: 64 cols (32 h0-f + 32 h1-f) x 256 K bf16
  {
    int col = tid & 63, kc = (tid >> 6) * 64;
    int wrow = (col < 32) ? (f0 + col) : (256 + f0 + col - 32);
    const unsigned short* src = Wt + (long)wrow * 256 + kc;
    unsigned short* d = &Bs[col * 264 + kc];
#pragma unroll
    for (int i = 0; i < 8; i++)
      *(u16x8*)(d + i * 8) = *(const u16x8*)(src + i * 8);
  }
  __syncthreads();

  // ---- GEMM with A-prefetch (distance 1 over ks)
  f32x4 acc[4][4] = {};
  const unsigned short* ax = xb + (Rw + lr) * 256 + qu * 8;
  fragA a_cur[4], a_nxt[4];
#pragma unroll
  for (int i = 0; i < 4; i++) a_cur[i] = *(const fragA*)(ax + i * 4096);
#pragma unroll
  for (int ks = 0; ks < 8; ks++) {
    if (ks < 7) {
#pragma unroll
      for (int i = 0; i < 4; i++)
        a_nxt[i] = *(const fragA*)(ax + i * 4096 + (ks + 1) * 32);
    }
    fragA bfr[4];
#pragma unroll
    for (int j = 0; j < 4; j++)
      bfr[j] = *(const fragA*)&Bs[(j * 16 + lr) * 264 + ks * 32 + qu * 8];
#pragma unroll
    for (int i = 0; i < 4; i++)
#pragma unroll
      for (int j = 0; j < 4; j++)
        acc[i][j] = __builtin_amdgcn_mfma_f32_16x16x32_bf16(a_cur[i], bfr[j], acc[i][j], 0, 0, 0);
#pragma unroll
    for (int i = 0; i < 4; i++) a_cur[i] = a_nxt[i];
  }

  // ---- h1 (cols 32..63) -> Hb[fl][b=wid][m]
#pragma unroll
  for (int i = 0; i < 4; i++) {
#pragma unroll
    for (int j = 2; j < 4; j++) {
      int fl = (j - 2) * 16 + lr;
      int m  = i * 16 + qu * 4;
      u16x4 pk;
      pk[0] = f2bf(acc[i][j][0]); pk[1] = f2bf(acc[i][j][1]);
      pk[2] = f2bf(acc[i][j][2]); pk[3] = f2bf(acc[i][j][3]);
      *(u16x4*)&Hb[fl * 296 + wid * 72 + m] = pk;
    }
  }
  __syncthreads();

  // ---- einsum: wave owns fl = wid*8+q. C[b,n] = sum_m h1[b,m]*off[n,m].
  // A rows wrapped (lr&3): rows 4..15 duplicate b 0..3, discarded.
  // Result stored in place: Hb[fl][b*72 + n].
  for (int q = 0; q < 8; q++) {
    int fl = wid * 8 + q;
    long fg = f0 + fl;
    const unsigned short* ob = offp + fg * 4096;
    fragA a0 = *(const fragA*)&Hb[fl * 296 + (lr & 3) * 72 + qu * 8];
    fragA a1 = *(const fragA*)&Hb[fl * 296 + (lr & 3) * 72 + 32 + qu * 8];
    fragA b0[4], b1[4];
#pragma unroll
    for (int ct = 0; ct < 4; ct++) {
      b0[ct] = *(const fragA*)(ob + (ct * 16 + lr) * 64 + qu * 8);
      b1[ct] = *(const fragA*)(ob + (ct * 16 + lr) * 64 + 32 + qu * 8);
    }
    f32x4 ea[4] = {};
#pragma unroll
    for (int ct = 0; ct < 4; ct++) {
      ea[ct] = __builtin_amdgcn_mfma_f32_16x16x32_bf16(a0, b0[ct], ea[ct], 0, 0, 0);
      ea[ct] = __builtin_amdgcn_mfma_f32_16x16x32_bf16(a1, b1[ct], ea[ct], 0, 0, 0);
    }
    if (qu == 0) {
#pragma unroll
      for (int ct = 0; ct < 4; ct++)
#pragma unroll
        for (int r = 0; r < 4; r++)
          Hb[fl * 296 + r * 72 + ct * 16 + lr] = f2bf(ea[ct][r]);
    }
  }
  __syncthreads();

  // ---- epilogue: out = d[n,f]*h0 + eins + bias
#pragma unroll
  for (int i = 0; i < 4; i++) {
#pragma unroll
    for (int j = 0; j < 2; j++) {
      int c = j * 16 + lr;
      int f = f0 + c;
      float bs = bias[f];
#pragma unroll
      for (int r = 0; r < 4; r++) {
        int m = i * 16 + qu * 4 + r;          // row within batch = n
        float ev = bf2f(Hb[c * 296 + wid * 72 + m]);
        out[(Rw + m) * 256 + f] = dscale[m * 256 + f] * acc[i][j][r] + ev + bs;
      }
    }
  }
}

// ---------------------------------------------------------------- launch
extern "C" void kernel_launch(void* const* d_in, const int* in_sizes, int n_in,
                              void* d_out, int out_size, void* d_ws, size_t ws_size,
                              hipStream_t stream) {
  const float* x    = (const float*)d_in[0];
  const float* W    = (const float*)d_in[1];
  const float* e    = (const float*)d_in[2];
  const float* bias = (const float*)d_in[3];
  const unsigned char* mask = (const unsigned char*)d_in[4];
  float* out = (float*)d_out;
  char* ws = (char*)d_ws;
  if (ws_size < (size_t)WS_NEED) return;

  k_pre<<<6176, 256, 0, stream>>>(x, e, W, mask, ws);
  k_main<<<4096, 256, 0, stream>>>(bias, ws, out);
}